// Round 11
// baseline (301.744 us; speedup 1.0000x reference)
//
#include <hip/hip_runtime.h>
#include <math.h>

#define NEG_INF -1000000000.0f

// ---------------------------------------------------------------------------
// Precompute kernel: blocks 0..63 -> posc (j-quad interleaved) ; blocks
// 64..191 -> tgtc[b][j] = target_emb[b] @ w_tgt.
// posc layout: posc[jq][s][4] (jq=j>>2) so the main kernel's per-lane (s)
// acc-init float4 loads are fully coalesced (16 B/lane, contiguous 1 KiB).
// ---------------------------------------------------------------------------
__global__ __launch_bounds__(64) void doe_pre_kernel(
    const float* __restrict__ pos_w1, const float* __restrict__ pos_b1,
    const float* __restrict__ pos_w2, const float* __restrict__ pos_b2,
    const float* __restrict__ att_w1, const float* __restrict__ att_b1,
    const float* __restrict__ target_emb,
    float* __restrict__ posc, float* __restrict__ tgtc)
{
    const int tid = threadIdx.x;
    if (blockIdx.x < 64) {
        const int s = blockIdx.x;
        __shared__ float p1[64];
        __shared__ float pe[64];
        float pos = (float)s * (1.0f / 63.0f);
        p1[tid] = fmaxf(fmaf(pos, pos_w1[tid], pos_b1[tid]), 0.0f);
        __syncthreads();
        float acc = pos_b2[tid];
        #pragma unroll
        for (int h = 0; h < 64; ++h) acc = fmaf(p1[h], pos_w2[h * 64 + tid], acc);
        pe[tid] = acc;
        __syncthreads();
        float pc = att_b1[tid];
        #pragma unroll
        for (int h = 0; h < 64; ++h) pc = fmaf(pe[h], att_w1[(64 + h) * 64 + tid], pc);
        posc[(tid >> 2) * 256 + s * 4 + (tid & 3)] = pc;   // [jq][s][4]
    } else {
        const int b = blockIdx.x - 64;
        const float* trow = target_emb + b * 64;   // wave-uniform -> s_load
        float acc = 0.0f;
        #pragma unroll
        for (int d = 0; d < 64; ++d) acc = fmaf(trow[d], att_w1[(128 + d) * 64 + tid], acc);
        tgtc[b * 64 + tid] = acc;
    }
}

// ---------------------------------------------------------------------------
// Main fused kernel, v5: zero LDS/barriers.
// R9 post-mortem: v4's VGPR collapsed to 44 -> no load-hoisting -> per-wave
// load-use serialization (waves 93% stalled); j-split row re-read added
// +165MB L2-miss traffic (FETCH 300MB). v5 inverts the register strategy:
// (256,4) = 128-reg budget; the WHOLE row is hoisted into 16 float4 regs
// once and kept live across both acc[32] j-halves (no re-read, loads fully
// amortized); column/proj phases batch-hoist 32 values at a time so one
// latency covers 32 loads. Peak live ~110 regs.
// ---------------------------------------------------------------------------
__device__ __forceinline__ void fma4rows32(float acc[32], const float4 a,
                                           const float* __restrict__ w0)
{
    #pragma unroll
    for (int j = 0; j < 32; ++j) {
        float t0 = fmaf(a.w, w0[192 + j], acc[j]);
        t0 = fmaf(a.z, w0[128 + j], t0);
        t0 = fmaf(a.y, w0[64 + j], t0);
        acc[j] = fmaf(a.x, w0[j], t0);
    }
}

__global__ __launch_bounds__(256, 4) void doe_main_kernel(
    const float* __restrict__ seg_emb, const int* __restrict__ smask,
    const float* __restrict__ att_w1, const float* __restrict__ att_w2,
    const float* __restrict__ att_b2, const float* __restrict__ proj_w,
    const float* __restrict__ proj_b, const float* __restrict__ ln_g,
    const float* __restrict__ ln_b, const float* __restrict__ posc,
    const float* __restrict__ tgtc, float* __restrict__ out)
{
    const int w    = threadIdx.x >> 6;
    const int lane = threadIdx.x & 63;
    const int g    = (blockIdx.x << 2) | w;   // tile id = b*64 + t
    const int b    = g >> 6;
    const int s    = lane;

    // ---- hoist the lane's whole row: 16 independent float4 loads, issued
    //      together; one HBM latency amortized over the entire GEMM ----
    const float4* rp4 = (const float4*)(seg_emb + (size_t)g * 4096 + s * 64);
    float4 row[16];
    #pragma unroll
    for (int i = 0; i < 16; ++i) row[i] = rp4[i];

    const int mval = smask[(g << 6) | s];

    float sc = att_b2[0];

    #pragma unroll 1
    for (int h = 0; h < 2; ++h) {
        const int jbase = h << 5;

        // ---- acc init: coalesced posc quads + wave-uniform tgtc s_loads ----
        float acc[32];
        {
            const float4* pq = (const float4*)posc + (h * 8) * 64 + s;
            const float*  tr = tgtc + b * 64 + jbase;
            #pragma unroll
            for (int jq = 0; jq < 8; ++jq) {
                float4 pv = pq[jq * 64];
                acc[4 * jq + 0] = pv.x + tr[4 * jq + 0];
                acc[4 * jq + 1] = pv.y + tr[4 * jq + 1];
                acc[4 * jq + 2] = pv.z + tr[4 * jq + 2];
                acc[4 * jq + 3] = pv.w + tr[4 * jq + 3];
            }
        }

        // ---- GEMM half: all 16 d-chunks from registers (row[] static) ----
        #pragma unroll
        for (int dc = 0; dc < 16; ++dc) {
            const float* wq = att_w1 + dc * 256 + jbase;   // uniform -> s_load
            fma4rows32(acc, row[dc], wq);
        }

        // ---- partial score over this j-half (4-way partials) ----
        const float* w2 = att_w2 + jbase;     // uniform -> s_load
        float s0 = 0.0f, s1 = 0.0f, s2 = 0.0f, s3 = 0.0f;
        #pragma unroll
        for (int jq = 0; jq < 8; ++jq) {
            s0 = fmaf(fmaxf(acc[4 * jq + 0], 0.0f), w2[4 * jq + 0], s0);
            s1 = fmaf(fmaxf(acc[4 * jq + 1], 0.0f), w2[4 * jq + 1], s1);
            s2 = fmaf(fmaxf(acc[4 * jq + 2], 0.0f), w2[4 * jq + 2], s2);
            s3 = fmaf(fmaxf(acc[4 * jq + 3], 0.0f), w2[4 * jq + 3], s3);
        }
        sc += (s0 + s1) + (s2 + s3);
    }

    if (mval == 0) sc = NEG_INF;

    // ---- wave softmax (all-masked row -> uniform 1/64, matches jax) ----
    float mx = sc;
    #pragma unroll
    for (int off = 32; off; off >>= 1) mx = fmaxf(mx, __shfl_xor(mx, off));
    float e = __expf(sc - mx);
    float sum = e;
    #pragma unroll
    for (int off = 32; off; off >>= 1) sum += __shfl_xor(sum, off);
    const float p = e / sum;                  // attn weight for row s=lane

    // ---- weighted sum over s: column re-reads, 32-value register batches
    //      (loads independent of shfl -> one latency per batch) ----
    const float* colb = seg_emb + (size_t)g * 4096 + lane;   // d = lane
    float v0 = 0.0f, v1 = 0.0f, v2 = 0.0f, v3 = 0.0f;
    #pragma unroll 1
    for (int half = 0; half < 2; ++half) {
        const int sb = half << 5;
        float cv[32];
        #pragma unroll
        for (int i = 0; i < 32; ++i) cv[i] = colb[(sb + i) * 64];
        #pragma unroll
        for (int i = 0; i < 8; ++i) {
            v0 = fmaf(__shfl(p, sb + 4 * i + 0), cv[4 * i + 0], v0);
            v1 = fmaf(__shfl(p, sb + 4 * i + 1), cv[4 * i + 1], v1);
            v2 = fmaf(__shfl(p, sb + 4 * i + 2), cv[4 * i + 2], v2);
            v3 = fmaf(__shfl(p, sb + 4 * i + 3), cv[4 * i + 3], v3);
        }
    }
    const float segv = (v0 + v1) + (v2 + v3);

    // ---- projection: segv broadcast + proj_w rows, 32-value batches ----
    const float* pw = proj_w + lane;
    float o0 = proj_b[lane], o1 = 0.0f, o2 = 0.0f, o3 = 0.0f;
    #pragma unroll 1
    for (int half = 0; half < 2; ++half) {
        const int db = half << 5;
        float pv_[32];
        #pragma unroll
        for (int i = 0; i < 32; ++i) pv_[i] = pw[(db + i) * 64];
        #pragma unroll
        for (int i = 0; i < 8; ++i) {
            o0 = fmaf(__shfl(segv, db + 4 * i + 0), pv_[4 * i + 0], o0);
            o1 = fmaf(__shfl(segv, db + 4 * i + 1), pv_[4 * i + 1], o1);
            o2 = fmaf(__shfl(segv, db + 4 * i + 2), pv_[4 * i + 2], o2);
            o3 = fmaf(__shfl(segv, db + 4 * i + 3), pv_[4 * i + 3], o3);
        }
    }
    const float o = (o0 + o1) + (o2 + o3);

    // ---- layernorm ----
    float ssum = o;
    #pragma unroll
    for (int off = 32; off; off >>= 1) ssum += __shfl_xor(ssum, off);
    float mu = ssum * (1.0f / 64.0f);
    float df = o - mu;
    float vsum = df * df;
    #pragma unroll
    for (int off = 32; off; off >>= 1) vsum += __shfl_xor(vsum, off);
    float var = vsum * (1.0f / 64.0f);
    float inv = 1.0f / sqrtf(var + 1e-5f);
    out[(g << 6) | lane] = fmaf(df * inv, ln_g[lane], ln_b[lane]);
}

extern "C" void kernel_launch(void* const* d_in, const int* in_sizes, int n_in,
                              void* d_out, int out_size, void* d_ws, size_t ws_size,
                              hipStream_t stream)
{
    const float* seg_emb    = (const float*)d_in[0];
    const int*   smask      = (const int*)  d_in[1];
    const float* target_emb = (const float*)d_in[2];
    const float* pos_w1     = (const float*)d_in[3];
    const float* pos_b1     = (const float*)d_in[4];
    const float* pos_w2     = (const float*)d_in[5];
    const float* pos_b2     = (const float*)d_in[6];
    const float* att_w1     = (const float*)d_in[7];
    const float* att_b1     = (const float*)d_in[8];
    const float* att_w2     = (const float*)d_in[9];
    const float* att_b2     = (const float*)d_in[10];
    const float* proj_w     = (const float*)d_in[11];
    const float* proj_b     = (const float*)d_in[12];
    const float* ln_g       = (const float*)d_in[13];
    const float* ln_b       = (const float*)d_in[14];
    float* out = (float*)d_out;

    float* posc = (float*)d_ws;        // 4096 floats, [jq][s][4] layout
    float* tgtc = posc + 4096;         // 8192 floats

    doe_pre_kernel<<<192, 64, 0, stream>>>(pos_w1, pos_b1, pos_w2, pos_b2,
                                           att_w1, att_b1, target_emb, posc, tgtc);
    doe_main_kernel<<<2048, 256, 0, stream>>>(seg_emb, smask, att_w1, att_w2,
                                              att_b2, proj_w, proj_b, ln_g, ln_b,
                                              posc, tgtc, out);
}